// Round 3
// baseline (1715.955 us; speedup 1.0000x reference)
//
#include <hip/hip_runtime.h>
#include <math.h>

// Belief propagation (sum-product) on dense H [E x N].
// Identity: output depends only on mu_c_to_v after ITERS=8 Jacobi steps,
// which equals (g.f)^4(0) -> 4 combined iterations.
// State: cn[c][v] = h*mu_c_to_v*w  (the only way mu enters anything).
// Column sums fused into the check kernel via HW f32 atomics into a
// triple-buffered accumulator; each check kernel zeroes the buffer needed
// two steps ahead (dead at that point; kernel boundary orders it).

constexpr int N = 4096;            // variable nodes
constexpr int E = 2048;            // check nodes
constexpr int CHUNK = 16;          // columns per thread in check kernel
constexpr int BT = N / CHUNK;      // 256 threads per check block
constexpr int NWAVES = BT / 64;    // 4

__global__ void prologue_kernel(const float* __restrict__ l_v, const float* __restrict__ b,
                                float* __restrict__ base, float* __restrict__ s1) {
    int v = blockIdx.x * blockDim.x + threadIdx.x;
    base[v] = l_v[v] * b[v];
    s1[v] = 0.f;
}

// One block per check row c.
// m = base (+ s_prev) - cn_row; T = h ? tanh(m/2) : 1;
// excl = exclusive row product (via product-of-nonzeros + zero count);
// msg = sign*2*atanh(excl); cn_new = h ? w*msg : 0; atomically add cn_new
// into s_acc (next iteration's column sums). Optionally zero s_zero.
template <bool FIRST, bool ZERO_NEXT>
__global__ __launch_bounds__(BT) void check_kernel(
    const int* __restrict__ h,            // used when FIRST
    unsigned short* __restrict__ hb,      // [E][BT] 16-bit masks
    const float* __restrict__ w,
    const int* __restrict__ s_c,
    const float* __restrict__ base,
    const float* __restrict__ s_prev,     // used when !FIRST
    float* __restrict__ s_acc,
    float* __restrict__ s_zero,           // used when ZERO_NEXT
    float* __restrict__ cn) {
    const int c = blockIdx.x;
    const int t = threadIdx.x;
    const int col0 = t * CHUNK;
    const size_t rowOff = (size_t)c * N;

    if (ZERO_NEXT && c < N / BT) s_zero[c * BT + t] = 0.f;

    unsigned int bits;
    float m[CHUNK];
    if (FIRST) {
        // build support mask from h row; stash for later iterations
        const int4* h4 = reinterpret_cast<const int4*>(h + rowOff + col0);
        bits = 0u;
        #pragma unroll
        for (int q = 0; q < 4; ++q) {
            int4 a = h4[q];
            bits |= (a.x != 0 ? 1u : 0u) << (4 * q + 0);
            bits |= (a.y != 0 ? 1u : 0u) << (4 * q + 1);
            bits |= (a.z != 0 ? 1u : 0u) << (4 * q + 2);
            bits |= (a.w != 0 ? 1u : 0u) << (4 * q + 3);
        }
        hb[c * BT + t] = (unsigned short)bits;
        const float4* b4 = reinterpret_cast<const float4*>(base + col0);
        #pragma unroll
        for (int q = 0; q < 4; ++q) {
            float4 a = b4[q];
            m[4*q+0] = a.x; m[4*q+1] = a.y; m[4*q+2] = a.z; m[4*q+3] = a.w;
        }
    } else {
        bits = hb[c * BT + t];
        const float4* b4 = reinterpret_cast<const float4*>(base + col0);
        const float4* s4 = reinterpret_cast<const float4*>(s_prev + col0);
        const float4* c4 = reinterpret_cast<const float4*>(cn + rowOff + col0);
        #pragma unroll
        for (int q = 0; q < 4; ++q) {
            float4 a = b4[q], s = s4[q], d = c4[q];
            m[4*q+0] = a.x + s.x - d.x; m[4*q+1] = a.y + s.y - d.y;
            m[4*q+2] = a.z + s.z - d.z; m[4*q+3] = a.w + s.w - d.w;
        }
    }

    // T = tanh(m/2) = (e^m - 1)/(e^m + 1) on fast pipes; clamp avoids inf/inf
    float T[CHUNK];
    float p = 1.f;
    int zc = 0;
    #pragma unroll
    for (int j = 0; j < CHUNK; ++j) {
        float mc = fminf(fmaxf(m[j], -30.f), 30.f);
        float em = __expf(mc);
        float th = (em - 1.f) * __builtin_amdgcn_rcpf(em + 1.f);
        float Tj = ((bits >> j) & 1u) ? th : 1.0f;
        T[j] = Tj;
        if (Tj == 0.f) zc++; else p *= Tj;
    }

    // wave butterfly reduce (product of nonzeros, zero count)
    #pragma unroll
    for (int s = 1; s < 64; s <<= 1) {
        p  *= __shfl_xor(p, s, 64);
        zc += __shfl_xor(zc, s, 64);
    }
    __shared__ float pw[NWAVES];
    __shared__ int   zw[NWAVES];
    const int wid = t >> 6;
    if ((t & 63) == 0) { pw[wid] = p; zw[wid] = zc; }
    __syncthreads();
    float P = 1.f;
    int  ZC = 0;
    #pragma unroll
    for (int u = 0; u < NWAVES; ++u) { P *= pw[u]; ZC += zw[u]; }

    const float sgn = (s_c[c] != 0) ? -1.f : 1.f;
    const float4* w4 = reinterpret_cast<const float4*>(w + rowOff + col0);
    float4 w0 = w4[0], w1 = w4[1], w2 = w4[2], w3 = w4[3];
    float wv[CHUNK] = {w0.x,w0.y,w0.z,w0.w, w1.x,w1.y,w1.z,w1.w,
                       w2.x,w2.y,w2.z,w2.w, w3.x,w3.y,w3.z,w3.w};

    float o[CHUNK];
    constexpr float LIM = 0.99999994f;   // 1 - 2^-24: guard div-path overshoot
    #pragma unroll
    for (int j = 0; j < CHUNK; ++j) {
        float excl;
        if (ZC == 0)      excl = fminf(fmaxf(__fdividef(P, T[j]), -LIM), LIM);
        else if (ZC == 1) excl = (T[j] == 0.f) ? P : 0.f;
        else              excl = 0.f;
        // sign*2*atanh(excl) = sign*ln((1+excl)/(1-excl)); log(1)=0 exactly
        float val = sgn * __logf(__fdividef(1.f + excl, 1.f - excl)) * wv[j];
        o[j] = ((bits >> j) & 1u) ? val : 0.f;
    }
    float4* o4 = reinterpret_cast<float4*>(cn + rowOff + col0);
    o4[0] = make_float4(o[0],  o[1],  o[2],  o[3]);
    o4[1] = make_float4(o[4],  o[5],  o[6],  o[7]);
    o4[2] = make_float4(o[8],  o[9],  o[10], o[11]);
    o4[3] = make_float4(o[12], o[13], o[14], o[15]);

    #pragma unroll
    for (int j = 0; j < CHUNK; ++j) {
        if ((bits >> j) & 1u) unsafeAtomicAdd(&s_acc[col0 + j], o[j]);
    }
}

__global__ void out_kernel(const float* __restrict__ base, const float* __restrict__ s,
                           float* __restrict__ outp) {
    int v = blockIdx.x * blockDim.x + threadIdx.x;
    outp[v] = 1.0f / (__expf(base[v] + s[v]) + 1.0f);   // hf_sigmoid
}

extern "C" void kernel_launch(void* const* d_in, const int* in_sizes, int n_in,
                              void* d_out, int out_size, void* d_ws, size_t ws_size,
                              hipStream_t stream) {
    const float* l_v = (const float*)d_in[0];
    const int*   h   = (const int*)d_in[1];
    const int*   s_c = (const int*)d_in[2];
    // d_in[3] = iterations (8 fixed; combined = 4)
    const float* b   = (const float*)d_in[4];
    const float* w   = (const float*)d_in[5];
    float* out = (float*)d_out;

    char* ws = (char*)d_ws;
    float* cn            = (float*)(ws);                         // 32 MB
    float* t0            = (float*)(ws + (size_t)E * N * 4);
    float* t1            = t0 + N;
    float* t2            = t1 + N;
    float* base          = t2 + N;
    unsigned short* hb   = (unsigned short*)(base + N);          // 1 MB

    // schedule: check_k reads s_{k-1}, accumulates s_k, zeroes s_{k+1}
    //   s1=t1 (zeroed in prologue), s2=t2, s3=t0, s4=t1
    prologue_kernel<<<N / 256, 256, 0, stream>>>(l_v, b, base, t1);
    check_kernel<true,  true ><<<E, BT, 0, stream>>>(h,       hb, w, s_c, base, nullptr, t1, t2, cn);
    check_kernel<false, true ><<<E, BT, 0, stream>>>(nullptr, hb, w, s_c, base, t1,      t2, t0, cn);
    check_kernel<false, true ><<<E, BT, 0, stream>>>(nullptr, hb, w, s_c, base, t2,      t0, t1, cn);
    check_kernel<false, false><<<E, BT, 0, stream>>>(nullptr, hb, w, s_c, base, t0,      t1, nullptr, cn);
    out_kernel<<<N / 256, 256, 0, stream>>>(base, t1, out);
}

// Round 5
// 731.543 us; speedup vs baseline: 2.3457x; 2.3457x over previous
//
#include <hip/hip_runtime.h>
#include <hip/hip_cooperative_groups.h>
#include <math.h>

namespace cg = cooperative_groups;

// Belief propagation (sum-product) on dense H [E x N].
// Identity: output depends only on mu_c_to_v after ITERS=8 Jacobi steps
// = (g.f)^4(0) -> 4 combined iterations.
// State: cn[c][v] = h*mu_c_to_v*w (the only way mu enters anything).
// Column sums via reduction tree (partial[G][N]) — NEVER same-address
// atomics (R3: 8x regression from 1024-way colliding atomics).
// Cooperative single-kernel (512 blocks, 2/CU needed vs 4 guaranteed);
// checked return code + discrete-kernel fallback (R4: unchecked coop
// launch failed -> poison output).

constexpr int N = 4096;
constexpr int E = 2048;
constexpr int CHUNK = 16;
constexpr int BT = 256;            // threads/block
constexpr int NWAVES = BT / 64;    // 4
constexpr int NBLK = 512;          // coop grid: 4 rows/block in phase A
constexpr int RPB = E / NBLK;      // 4
constexpr int G = 8;               // colsum row-groups (256 rows each)
constexpr int ITER = 4;

// ---------- phase A: check update for RPB consecutive rows ----------
template <bool FIRST>
__device__ __forceinline__ void phaseA_body(
    int blk, int t,
    const float* __restrict__ l_v, const int* __restrict__ h,
    const int* __restrict__ s_c, const float* __restrict__ bv,
    const float* __restrict__ w, const float* __restrict__ partial,
    unsigned short* __restrict__ hb, float* __restrict__ cn)
{
    const int col0 = t * CHUNK;
    __shared__ float pw[NWAVES];
    __shared__ int   zw[NWAVES];

    // tot[j] = l_v*b (+ colsums from partial when !FIRST), shared by all rows
    float tot[CHUNK];
    {
        const float4* lv4 = reinterpret_cast<const float4*>(l_v + col0);
        const float4* bb4 = reinterpret_cast<const float4*>(bv + col0);
        #pragma unroll
        for (int q = 0; q < 4; ++q) {
            float4 a = lv4[q], d = bb4[q];
            tot[4*q+0] = a.x*d.x; tot[4*q+1] = a.y*d.y;
            tot[4*q+2] = a.z*d.z; tot[4*q+3] = a.w*d.w;
        }
    }
    if (!FIRST) {
        #pragma unroll
        for (int g = 0; g < G; ++g) {
            const float4* p4 = reinterpret_cast<const float4*>(partial + g * N + col0);
            #pragma unroll
            for (int q = 0; q < 4; ++q) {
                float4 a = p4[q];
                tot[4*q+0] += a.x; tot[4*q+1] += a.y;
                tot[4*q+2] += a.z; tot[4*q+3] += a.w;
            }
        }
    }

    #pragma unroll 1
    for (int rr = 0; rr < RPB; ++rr) {
        const int c = blk * RPB + rr;
        const size_t rowOff = (size_t)c * N;

        unsigned int bits;
        float m[CHUNK];
        if (FIRST) {
            const int4* h4 = reinterpret_cast<const int4*>(h + rowOff + col0);
            bits = 0u;
            #pragma unroll
            for (int q = 0; q < 4; ++q) {
                int4 a = h4[q];
                bits |= (a.x != 0 ? 1u : 0u) << (4*q+0);
                bits |= (a.y != 0 ? 1u : 0u) << (4*q+1);
                bits |= (a.z != 0 ? 1u : 0u) << (4*q+2);
                bits |= (a.w != 0 ? 1u : 0u) << (4*q+3);
            }
            hb[c * BT + t] = (unsigned short)bits;
            #pragma unroll
            for (int j = 0; j < CHUNK; ++j) m[j] = tot[j];
        } else {
            bits = hb[c * BT + t];
            const float4* c4 = reinterpret_cast<const float4*>(cn + rowOff + col0);
            #pragma unroll
            for (int q = 0; q < 4; ++q) {
                float4 d = c4[q];
                m[4*q+0] = tot[4*q+0] - d.x; m[4*q+1] = tot[4*q+1] - d.y;
                m[4*q+2] = tot[4*q+2] - d.z; m[4*q+3] = tot[4*q+3] - d.w;
            }
        }

        // T = tanh(m/2) = (e^m - 1)/(e^m + 1) on fast pipes
        float T[CHUNK];
        float p = 1.f; int zc = 0;
        #pragma unroll
        for (int j = 0; j < CHUNK; ++j) {
            float mc = fminf(fmaxf(m[j], -30.f), 30.f);
            float em = __expf(mc);
            float th = (em - 1.f) * __builtin_amdgcn_rcpf(em + 1.f);
            float Tj = ((bits >> j) & 1u) ? th : 1.0f;
            T[j] = Tj;
            if (Tj == 0.f) zc++; else p *= Tj;
        }
        // wave butterfly (product of nonzeros, zero count), then cross-wave
        #pragma unroll
        for (int s = 1; s < 64; s <<= 1) {
            p  *= __shfl_xor(p, s, 64);
            zc += __shfl_xor(zc, s, 64);
        }
        const int wid = t >> 6;
        if ((t & 63) == 0) { pw[wid] = p; zw[wid] = zc; }
        __syncthreads();
        float P = 1.f; int ZC = 0;
        #pragma unroll
        for (int u = 0; u < NWAVES; ++u) { P *= pw[u]; ZC += zw[u]; }
        __syncthreads();   // pw/zw reused next row

        const float sgn = (s_c[c] != 0) ? -1.f : 1.f;
        const float4* w4 = reinterpret_cast<const float4*>(w + rowOff + col0);
        float o[CHUNK];
        constexpr float LIM = 0.99999994f;   // 1 - 2^-24
        #pragma unroll
        for (int q = 0; q < 4; ++q) {
            float4 wq = w4[q];
            float wv[4] = {wq.x, wq.y, wq.z, wq.w};
            #pragma unroll
            for (int u = 0; u < 4; ++u) {
                int j = 4*q + u;
                float excl;
                if (ZC == 0)      excl = fminf(fmaxf(__fdividef(P, T[j]), -LIM), LIM);
                else if (ZC == 1) excl = (T[j] == 0.f) ? P : 0.f;
                else              excl = 0.f;
                // sign*2*atanh(x) = sign*ln((1+x)/(1-x)); log(1)=0 exactly
                float val = sgn * __logf(__fdividef(1.f + excl, 1.f - excl)) * wv[u];
                o[j] = ((bits >> j) & 1u) ? val : 0.f;
            }
        }
        float4* o4 = reinterpret_cast<float4*>(cn + rowOff + col0);
        #pragma unroll
        for (int q = 0; q < 4; ++q)
            o4[q] = make_float4(o[4*q+0], o[4*q+1], o[4*q+2], o[4*q+3]);
    }
}

// ---------- phase B: partial column sums, all NBLK blocks ----------
__device__ __forceinline__ void phaseB_body(
    int blk, int t, const float* __restrict__ cn, float* __restrict__ partial)
{
    const int g  = blk >> 6;          // row group (256 rows)
    const int ch = blk & 63;          // col chunk (16 float4-cols)
    const int cidx  = t & 15;         // col within chunk
    const int slice = t >> 4;         // 16-row slice within group
    const int col4 = ch * 16 + cidx;

    const float4* cp = reinterpret_cast<const float4*>(cn)
                       + (size_t)(g * 256 + slice * 16) * (N / 4) + col4;
    float4 s = make_float4(0.f, 0.f, 0.f, 0.f);
    #pragma unroll
    for (int r = 0; r < 16; ++r) {
        float4 v = cp[(size_t)r * (N / 4)];
        s.x += v.x; s.y += v.y; s.z += v.z; s.w += v.w;
    }
    __shared__ float4 red[16][16];
    red[slice][cidx] = s;
    __syncthreads();
    #pragma unroll
    for (int hh = 8; hh >= 1; hh >>= 1) {
        if (slice < hh) {
            float4 a = red[slice][cidx], bq = red[slice + hh][cidx];
            red[slice][cidx] = make_float4(a.x + bq.x, a.y + bq.y, a.z + bq.z, a.w + bq.w);
        }
        __syncthreads();
    }
    if (slice == 0)
        reinterpret_cast<float4*>(partial + g * N)[col4] = red[0][cidx];
}

__device__ __forceinline__ void phaseOut_body(
    int blk, int t, const float* __restrict__ l_v, const float* __restrict__ bv,
    const float* __restrict__ partial, float* __restrict__ out)
{
    const int v = blk * BT + t;
    float s = l_v[v] * bv[v];
    #pragma unroll
    for (int g = 0; g < G; ++g) s += partial[g * N + v];
    out[v] = 1.0f / (__expf(s) + 1.0f);   // hf_sigmoid
}

// ---------- cooperative single-kernel ----------
__global__ __launch_bounds__(BT, 4) void bp_coop(
    const float* __restrict__ l_v, const int* __restrict__ h,
    const int* __restrict__ s_c, const float* __restrict__ bv,
    const float* __restrict__ w, float* __restrict__ out,
    float* __restrict__ cn, float* __restrict__ partial,
    unsigned short* __restrict__ hb)
{
    cg::grid_group grid = cg::this_grid();
    const int blk = blockIdx.x, t = threadIdx.x;

    phaseA_body<true>(blk, t, l_v, h, s_c, bv, w, partial, hb, cn);
    grid.sync();
    phaseB_body(blk, t, cn, partial);
    grid.sync();
    #pragma unroll 1
    for (int it = 1; it < ITER; ++it) {
        phaseA_body<false>(blk, t, l_v, h, s_c, bv, w, partial, hb, cn);
        grid.sync();
        phaseB_body(blk, t, cn, partial);
        grid.sync();
    }
    if (blk < N / BT) phaseOut_body(blk, t, l_v, bv, partial, out);
}

// ---------- discrete fallback kernels (same bodies) ----------
template <bool FIRST>
__global__ __launch_bounds__(BT, 4) void kA(
    const float* __restrict__ l_v, const int* __restrict__ h,
    const int* __restrict__ s_c, const float* __restrict__ bv,
    const float* __restrict__ w, const float* __restrict__ partial,
    unsigned short* __restrict__ hb, float* __restrict__ cn)
{
    phaseA_body<FIRST>(blockIdx.x, threadIdx.x, l_v, h, s_c, bv, w, partial, hb, cn);
}

__global__ __launch_bounds__(BT, 4) void kB(
    const float* __restrict__ cn, float* __restrict__ partial)
{
    phaseB_body(blockIdx.x, threadIdx.x, cn, partial);
}

__global__ void kOut(const float* __restrict__ l_v, const float* __restrict__ bv,
                     const float* __restrict__ partial, float* __restrict__ out)
{
    phaseOut_body(blockIdx.x, threadIdx.x, l_v, bv, partial, out);
}

extern "C" void kernel_launch(void* const* d_in, const int* in_sizes, int n_in,
                              void* d_out, int out_size, void* d_ws, size_t ws_size,
                              hipStream_t stream) {
    const float* l_v = (const float*)d_in[0];
    const int*   h   = (const int*)d_in[1];
    const int*   s_c = (const int*)d_in[2];
    // d_in[3] = iterations (8 fixed; combined = 4)
    const float* bv  = (const float*)d_in[4];
    const float* w   = (const float*)d_in[5];
    float* out = (float*)d_out;

    char* ws = (char*)d_ws;
    float* cn          = (float*)(ws);                              // 32 MB
    float* partial     = (float*)(ws + (size_t)E * N * 4);          // 128 KB
    unsigned short* hb = (unsigned short*)(ws + (size_t)E * N * 4 + (size_t)G * N * 4); // 1 MB

    void* args[] = {(void*)&l_v, (void*)&h, (void*)&s_c, (void*)&bv,
                    (void*)&w, (void*)&out, (void*)&cn, (void*)&partial, (void*)&hb};
    hipError_t e = hipLaunchCooperativeKernel((const void*)bp_coop,
                                              dim3(NBLK), dim3(BT), args, 0, stream);
    if (e != hipSuccess) {
        // deterministic fallback: identical math, discrete launches
        kA<true><<<NBLK, BT, 0, stream>>>(l_v, h, s_c, bv, w, partial, hb, cn);
        kB<<<NBLK, BT, 0, stream>>>(cn, partial);
        for (int it = 1; it < ITER; ++it) {
            kA<false><<<NBLK, BT, 0, stream>>>(l_v, h, s_c, bv, w, partial, hb, cn);
            kB<<<NBLK, BT, 0, stream>>>(cn, partial);
        }
        kOut<<<N / BT, BT, 0, stream>>>(l_v, bv, partial, out);
    }
}

// Round 7
// 211.752 us; speedup vs baseline: 8.1036x; 3.4547x over previous
//
#include <hip/hip_runtime.h>
#include <math.h>

// Belief propagation (sum-product) on dense H [E x N].
// Identity: output depends only on mu_c_to_v after ITERS=8 Jacobi steps
// = (g.f)^4(0) -> 4 combined iterations.
// State: cn[c][v] = h*mu_c_to_v*w (the only way mu enters anything).
// Discrete 8-node pipeline: kA (per-row check update) alternating with
// kT (full column-sum -> total[v] = l_v*b + colsum, final one -> sigmoid out).
// NO same-address atomics (R3: 8x regression). NO cooperative grid.sync
// (R5: device-scope fences flush non-coherent per-XCD L2s -> 206 MB HBM
// refetch, 3x regression).

constexpr int N = 4096;
constexpr int E = 2048;
constexpr int CHUNK = 16;
constexpr int BT = 256;            // threads/block (check)
constexpr int NWAVES = BT / 64;    // 4

// ---------- kA: check update, one block per row ----------
template <bool FIRST>
__global__ __launch_bounds__(BT) void kA(
    const float* __restrict__ l_v, const int* __restrict__ h,
    const int* __restrict__ s_c, const float* __restrict__ bv,
    const float* __restrict__ w, const float* __restrict__ total,
    unsigned short* __restrict__ hb, float* __restrict__ cn)
{
    const int c = blockIdx.x;
    const int t = threadIdx.x;
    const int col0 = t * CHUNK;
    const size_t rowOff = (size_t)c * N;

    unsigned int bits;
    float m[CHUNK];
    if (FIRST) {
        const int4* h4 = reinterpret_cast<const int4*>(h + rowOff + col0);
        bits = 0u;
        #pragma unroll
        for (int q = 0; q < 4; ++q) {
            int4 a = h4[q];
            bits |= (a.x != 0 ? 1u : 0u) << (4*q+0);
            bits |= (a.y != 0 ? 1u : 0u) << (4*q+1);
            bits |= (a.z != 0 ? 1u : 0u) << (4*q+2);
            bits |= (a.w != 0 ? 1u : 0u) << (4*q+3);
        }
        hb[c * BT + t] = (unsigned short)bits;
        const float4* lv4 = reinterpret_cast<const float4*>(l_v + col0);
        const float4* bb4 = reinterpret_cast<const float4*>(bv + col0);
        #pragma unroll
        for (int q = 0; q < 4; ++q) {
            float4 a = lv4[q], d = bb4[q];
            m[4*q+0] = a.x*d.x; m[4*q+1] = a.y*d.y;
            m[4*q+2] = a.z*d.z; m[4*q+3] = a.w*d.w;
        }
    } else {
        bits = hb[c * BT + t];
        const float4* t4 = reinterpret_cast<const float4*>(total + col0);
        const float4* c4 = reinterpret_cast<const float4*>(cn + rowOff + col0);
        #pragma unroll
        for (int q = 0; q < 4; ++q) {
            float4 a = t4[q], d = c4[q];
            m[4*q+0] = a.x - d.x; m[4*q+1] = a.y - d.y;
            m[4*q+2] = a.z - d.z; m[4*q+3] = a.w - d.w;
        }
    }

    // T = tanh(m/2) = (e^m - 1)/(e^m + 1) on fast pipes
    float T[CHUNK];
    float p = 1.f; int zc = 0;
    #pragma unroll
    for (int j = 0; j < CHUNK; ++j) {
        float mc = fminf(fmaxf(m[j], -30.f), 30.f);
        float em = __expf(mc);
        float th = (em - 1.f) * __builtin_amdgcn_rcpf(em + 1.f);
        float Tj = ((bits >> j) & 1u) ? th : 1.0f;
        T[j] = Tj;
        if (Tj == 0.f) zc++; else p *= Tj;
    }
    // wave butterfly (product of nonzeros, zero count), then cross-wave
    #pragma unroll
    for (int s = 1; s < 64; s <<= 1) {
        p  *= __shfl_xor(p, s, 64);
        zc += __shfl_xor(zc, s, 64);
    }
    __shared__ float pw[NWAVES];
    __shared__ int   zw[NWAVES];
    const int wid = t >> 6;
    if ((t & 63) == 0) { pw[wid] = p; zw[wid] = zc; }
    __syncthreads();
    float P = 1.f; int ZC = 0;
    #pragma unroll
    for (int u = 0; u < NWAVES; ++u) { P *= pw[u]; ZC += zw[u]; }

    const float sgn = (s_c[c] != 0) ? -1.f : 1.f;
    const float4* w4 = reinterpret_cast<const float4*>(w + rowOff + col0);
    float o[CHUNK];
    constexpr float LIM = 0.99999994f;   // 1 - 2^-24: guard div-path overshoot
    #pragma unroll
    for (int q = 0; q < 4; ++q) {
        float4 wq = w4[q];
        float wv[4] = {wq.x, wq.y, wq.z, wq.w};
        #pragma unroll
        for (int u = 0; u < 4; ++u) {
            int j = 4*q + u;
            float excl;
            if (ZC == 0)      excl = fminf(fmaxf(__fdividef(P, T[j]), -LIM), LIM);
            else if (ZC == 1) excl = (T[j] == 0.f) ? P : 0.f;
            else              excl = 0.f;
            // sign*2*atanh(x) = sign*ln((1+x)/(1-x)); log(1)=0 exactly
            float val = sgn * __logf(__fdividef(1.f + excl, 1.f - excl)) * wv[u];
            o[j] = ((bits >> j) & 1u) ? val : 0.f;
        }
    }
    float4* o4 = reinterpret_cast<float4*>(cn + rowOff + col0);
    #pragma unroll
    for (int q = 0; q < 4; ++q)
        o4[q] = make_float4(o[4*q+0], o[4*q+1], o[4*q+2], o[4*q+3]);
}

// ---------- kT: full column sum -> total (or sigmoid out), 128 blocks ----------
// Block owns 8 float4-cols (128 B wide); 256 threads = 8 cidx x 32 slices,
// each slice accumulates 64 rows; LDS tree over slices.
constexpr int T_BLOCKS = 128;
constexpr int T_F4C = 8;            // float4-cols per block
constexpr int T_SLICES = 32;
constexpr int T_ROWS = E / T_SLICES; // 64

template <bool FINAL>
__global__ __launch_bounds__(BT) void kT(
    const float* __restrict__ cn, const float* __restrict__ l_v,
    const float* __restrict__ bv, float* __restrict__ total,
    float* __restrict__ out)
{
    const int t = threadIdx.x;
    const int cidx  = t & (T_F4C - 1);       // 0..7
    const int slice = t >> 3;                // 0..31
    const int f4c = blockIdx.x * T_F4C + cidx;

    const float4* cp = reinterpret_cast<const float4*>(cn)
                       + (size_t)(slice * T_ROWS) * (N / 4) + f4c;
    float4 s = make_float4(0.f, 0.f, 0.f, 0.f);
    #pragma unroll 8
    for (int r = 0; r < T_ROWS; ++r) {
        float4 v = cp[(size_t)r * (N / 4)];
        s.x += v.x; s.y += v.y; s.z += v.z; s.w += v.w;
    }
    __shared__ float4 red[T_SLICES][T_F4C];
    red[slice][cidx] = s;
    __syncthreads();
    #pragma unroll
    for (int hh = T_SLICES / 2; hh >= 1; hh >>= 1) {
        if (slice < hh) {
            float4 a = red[slice][cidx], b = red[slice + hh][cidx];
            red[slice][cidx] = make_float4(a.x + b.x, a.y + b.y, a.z + b.z, a.w + b.w);
        }
        __syncthreads();
    }
    if (t < T_F4C) {
        float4 sum = red[0][t];
        const int col = (blockIdx.x * T_F4C + t) * 4;
        float4 lv = *reinterpret_cast<const float4*>(l_v + col);
        float4 bb = *reinterpret_cast<const float4*>(bv + col);
        float4 r = make_float4(lv.x*bb.x + sum.x, lv.y*bb.y + sum.y,
                               lv.z*bb.z + sum.z, lv.w*bb.w + sum.w);
        if (FINAL) {
            r = make_float4(1.f/(__expf(r.x)+1.f), 1.f/(__expf(r.y)+1.f),
                            1.f/(__expf(r.z)+1.f), 1.f/(__expf(r.w)+1.f));
            *reinterpret_cast<float4*>(out + col) = r;
        } else {
            *reinterpret_cast<float4*>(total + col) = r;
        }
    }
}

extern "C" void kernel_launch(void* const* d_in, const int* in_sizes, int n_in,
                              void* d_out, int out_size, void* d_ws, size_t ws_size,
                              hipStream_t stream) {
    const float* l_v = (const float*)d_in[0];
    const int*   h   = (const int*)d_in[1];
    const int*   s_c = (const int*)d_in[2];
    // d_in[3] = iterations (8 fixed; combined = 4)
    const float* bv  = (const float*)d_in[4];
    const float* w   = (const float*)d_in[5];
    float* out = (float*)d_out;

    char* ws = (char*)d_ws;
    float* cn          = (float*)(ws);                            // 32 MB
    float* total       = (float*)(ws + (size_t)E * N * 4);        // 16 KB
    unsigned short* hb = (unsigned short*)(ws + (size_t)E * N * 4 + (size_t)N * 4); // 1 MB

    kA<true ><<<E, BT, 0, stream>>>(l_v, h, s_c, bv, w, total, hb, cn);
    kT<false><<<T_BLOCKS, BT, 0, stream>>>(cn, l_v, bv, total, out);
    kA<false><<<E, BT, 0, stream>>>(l_v, h, s_c, bv, w, total, hb, cn);
    kT<false><<<T_BLOCKS, BT, 0, stream>>>(cn, l_v, bv, total, out);
    kA<false><<<E, BT, 0, stream>>>(l_v, h, s_c, bv, w, total, hb, cn);
    kT<false><<<T_BLOCKS, BT, 0, stream>>>(cn, l_v, bv, total, out);
    kA<false><<<E, BT, 0, stream>>>(l_v, h, s_c, bv, w, total, hb, cn);
    kT<true ><<<T_BLOCKS, BT, 0, stream>>>(cn, l_v, bv, total, out);
}

// Round 9
// 210.473 us; speedup vs baseline: 8.1528x; 1.0061x over previous
//
#include <hip/hip_runtime.h>
#include <math.h>

// Belief propagation (sum-product) on dense H [E x N].
// Identity: output depends only on mu_c_to_v after ITERS=8 Jacobi steps
// = (g.f)^4(0) -> 4 combined iterations.
// State: cn[c][v] = h*mu_c_to_v*w (the only way mu enters anything).
// Discrete 8-node pipeline: kA (per-row check update) alternating with
// kT (full column-sum -> total, final one fuses sigmoid -> out).
// NO same-address atomics (R3: 8x regression). NO cooperative grid.sync
// (R5: L2-flush -> 206 MB HBM refetch, 3x regression).
// R8: kA issues ALL global loads up front — R7 budget analysis put kA at
// ~40 us (2.3 TB/s on 96 MB L3-resident), latency-bound on the w-row load
// that sat after the cross-wave reduce (two barriers) on the critical path.

constexpr int N = 4096;
constexpr int E = 2048;
constexpr int CHUNK = 16;
constexpr int BT = 256;            // threads/block (check)
constexpr int NWAVES = BT / 64;    // 4

// ---------- kA: check update, one block per row ----------
template <bool FIRST>
__global__ __launch_bounds__(BT) void kA(
    const float* __restrict__ l_v, const int* __restrict__ h,
    const int* __restrict__ s_c, const float* __restrict__ bv,
    const float* __restrict__ w, const float* __restrict__ total,
    unsigned short* __restrict__ hb, float* __restrict__ cn)
{
    const int c = blockIdx.x;
    const int t = threadIdx.x;
    const int col0 = t * CHUNK;
    const size_t rowOff = (size_t)c * N;

    // ---- issue ALL global loads back-to-back before any compute ----
    unsigned int bits;
    float m[CHUNK];
    float4 wreg[4];
    const float4* w4p = reinterpret_cast<const float4*>(w + rowOff + col0);
    if (FIRST) {
        const int4* h4 = reinterpret_cast<const int4*>(h + rowOff + col0);
        int4 hh0 = h4[0], hh1 = h4[1], hh2 = h4[2], hh3 = h4[3];
        const float4* lv4 = reinterpret_cast<const float4*>(l_v + col0);
        const float4* bb4 = reinterpret_cast<const float4*>(bv + col0);
        float4 a0 = lv4[0], a1 = lv4[1], a2 = lv4[2], a3 = lv4[3];
        float4 d0 = bb4[0], d1 = bb4[1], d2 = bb4[2], d3 = bb4[3];
        #pragma unroll
        for (int q = 0; q < 4; ++q) wreg[q] = w4p[q];

        bits = 0u;
        int4 hh[4] = {hh0, hh1, hh2, hh3};
        #pragma unroll
        for (int q = 0; q < 4; ++q) {
            bits |= (hh[q].x != 0 ? 1u : 0u) << (4*q+0);
            bits |= (hh[q].y != 0 ? 1u : 0u) << (4*q+1);
            bits |= (hh[q].z != 0 ? 1u : 0u) << (4*q+2);
            bits |= (hh[q].w != 0 ? 1u : 0u) << (4*q+3);
        }
        hb[c * BT + t] = (unsigned short)bits;
        float4 av[4] = {a0, a1, a2, a3};
        float4 dv[4] = {d0, d1, d2, d3};
        #pragma unroll
        for (int q = 0; q < 4; ++q) {
            m[4*q+0] = av[q].x * dv[q].x; m[4*q+1] = av[q].y * dv[q].y;
            m[4*q+2] = av[q].z * dv[q].z; m[4*q+3] = av[q].w * dv[q].w;
        }
    } else {
        bits = hb[c * BT + t];
        const float4* t4 = reinterpret_cast<const float4*>(total + col0);
        const float4* c4 = reinterpret_cast<const float4*>(cn + rowOff + col0);
        float4 a0 = t4[0], a1 = t4[1], a2 = t4[2], a3 = t4[3];
        float4 d0 = c4[0], d1 = c4[1], d2 = c4[2], d3 = c4[3];
        #pragma unroll
        for (int q = 0; q < 4; ++q) wreg[q] = w4p[q];
        float4 av[4] = {a0, a1, a2, a3};
        float4 dv[4] = {d0, d1, d2, d3};
        #pragma unroll
        for (int q = 0; q < 4; ++q) {
            m[4*q+0] = av[q].x - dv[q].x; m[4*q+1] = av[q].y - dv[q].y;
            m[4*q+2] = av[q].z - dv[q].z; m[4*q+3] = av[q].w - dv[q].w;
        }
    }

    // T = tanh(m/2) = (e^m - 1)/(e^m + 1) on fast pipes
    float T[CHUNK];
    float p = 1.f; int zc = 0;
    #pragma unroll
    for (int j = 0; j < CHUNK; ++j) {
        float mc = fminf(fmaxf(m[j], -30.f), 30.f);
        float em = __expf(mc);
        float th = (em - 1.f) * __builtin_amdgcn_rcpf(em + 1.f);
        float Tj = ((bits >> j) & 1u) ? th : 1.0f;
        T[j] = Tj;
        if (Tj == 0.f) zc++; else p *= Tj;
    }
    // wave butterfly (product of nonzeros, zero count), then cross-wave
    #pragma unroll
    for (int s = 1; s < 64; s <<= 1) {
        p  *= __shfl_xor(p, s, 64);
        zc += __shfl_xor(zc, s, 64);
    }
    __shared__ float pw[NWAVES];
    __shared__ int   zw[NWAVES];
    const int wid = t >> 6;
    if ((t & 63) == 0) { pw[wid] = p; zw[wid] = zc; }
    __syncthreads();
    float P = 1.f; int ZC = 0;
    #pragma unroll
    for (int u = 0; u < NWAVES; ++u) { P *= pw[u]; ZC += zw[u]; }

    const float sgn = (s_c[c] != 0) ? -1.f : 1.f;
    float o[CHUNK];
    constexpr float LIM = 0.99999994f;   // 1 - 2^-24: guard div-path overshoot
    #pragma unroll
    for (int q = 0; q < 4; ++q) {
        float wv[4] = {wreg[q].x, wreg[q].y, wreg[q].z, wreg[q].w};
        #pragma unroll
        for (int u = 0; u < 4; ++u) {
            int j = 4*q + u;
            float excl;
            if (ZC == 0)      excl = fminf(fmaxf(__fdividef(P, T[j]), -LIM), LIM);
            else if (ZC == 1) excl = (T[j] == 0.f) ? P : 0.f;
            else              excl = 0.f;
            // sign*2*atanh(x) = sign*ln((1+x)/(1-x)); log(1)=0 exactly
            float val = sgn * __logf(__fdividef(1.f + excl, 1.f - excl)) * wv[u];
            o[j] = ((bits >> j) & 1u) ? val : 0.f;
        }
    }
    float4* o4 = reinterpret_cast<float4*>(cn + rowOff + col0);
    #pragma unroll
    for (int q = 0; q < 4; ++q)
        o4[q] = make_float4(o[4*q+0], o[4*q+1], o[4*q+2], o[4*q+3]);
}

// ---------- kT: full column sum -> total (or sigmoid out), 128 blocks ----------
// Block owns 8 float4-cols (128 B wide); 256 threads = 8 cidx x 32 slices,
// each slice accumulates 64 rows; LDS tree over slices.
constexpr int T_BLOCKS = 128;
constexpr int T_F4C = 8;            // float4-cols per block
constexpr int T_SLICES = 32;
constexpr int T_ROWS = E / T_SLICES; // 64

template <bool FINAL>
__global__ __launch_bounds__(BT) void kT(
    const float* __restrict__ cn, const float* __restrict__ l_v,
    const float* __restrict__ bv, float* __restrict__ total,
    float* __restrict__ out)
{
    const int t = threadIdx.x;
    const int cidx  = t & (T_F4C - 1);       // 0..7
    const int slice = t >> 3;                // 0..31
    const int f4c = blockIdx.x * T_F4C + cidx;

    const float4* cp = reinterpret_cast<const float4*>(cn)
                       + (size_t)(slice * T_ROWS) * (N / 4) + f4c;
    float4 s = make_float4(0.f, 0.f, 0.f, 0.f);
    #pragma unroll 8
    for (int r = 0; r < T_ROWS; ++r) {
        float4 v = cp[(size_t)r * (N / 4)];
        s.x += v.x; s.y += v.y; s.z += v.z; s.w += v.w;
    }
    __shared__ float4 red[T_SLICES][T_F4C];
    red[slice][cidx] = s;
    __syncthreads();
    #pragma unroll
    for (int hh = T_SLICES / 2; hh >= 1; hh >>= 1) {
        if (slice < hh) {
            float4 a = red[slice][cidx], b = red[slice + hh][cidx];
            red[slice][cidx] = make_float4(a.x + b.x, a.y + b.y, a.z + b.z, a.w + b.w);
        }
        __syncthreads();
    }
    if (t < T_F4C) {
        float4 sum = red[0][t];
        const int col = (blockIdx.x * T_F4C + t) * 4;
        float4 lv = *reinterpret_cast<const float4*>(l_v + col);
        float4 bb = *reinterpret_cast<const float4*>(bv + col);
        float4 r = make_float4(lv.x*bb.x + sum.x, lv.y*bb.y + sum.y,
                               lv.z*bb.z + sum.z, lv.w*bb.w + sum.w);
        if (FINAL) {
            r = make_float4(1.f/(__expf(r.x)+1.f), 1.f/(__expf(r.y)+1.f),
                            1.f/(__expf(r.z)+1.f), 1.f/(__expf(r.w)+1.f));
            *reinterpret_cast<float4*>(out + col) = r;
        } else {
            *reinterpret_cast<float4*>(total + col) = r;
        }
    }
}

extern "C" void kernel_launch(void* const* d_in, const int* in_sizes, int n_in,
                              void* d_out, int out_size, void* d_ws, size_t ws_size,
                              hipStream_t stream) {
    const float* l_v = (const float*)d_in[0];
    const int*   h   = (const int*)d_in[1];
    const int*   s_c = (const int*)d_in[2];
    // d_in[3] = iterations (8 fixed; combined = 4)
    const float* bv  = (const float*)d_in[4];
    const float* w   = (const float*)d_in[5];
    float* out = (float*)d_out;

    char* ws = (char*)d_ws;
    float* cn          = (float*)(ws);                            // 32 MB
    float* total       = (float*)(ws + (size_t)E * N * 4);        // 16 KB
    unsigned short* hb = (unsigned short*)(ws + (size_t)E * N * 4 + (size_t)N * 4); // 1 MB

    kA<true ><<<E, BT, 0, stream>>>(l_v, h, s_c, bv, w, total, hb, cn);
    kT<false><<<T_BLOCKS, BT, 0, stream>>>(cn, l_v, bv, total, out);
    kA<false><<<E, BT, 0, stream>>>(l_v, h, s_c, bv, w, total, hb, cn);
    kT<false><<<T_BLOCKS, BT, 0, stream>>>(cn, l_v, bv, total, out);
    kA<false><<<E, BT, 0, stream>>>(l_v, h, s_c, bv, w, total, hb, cn);
    kT<false><<<T_BLOCKS, BT, 0, stream>>>(cn, l_v, bv, total, out);
    kA<false><<<E, BT, 0, stream>>>(l_v, h, s_c, bv, w, total, hb, cn);
    kT<true ><<<T_BLOCKS, BT, 0, stream>>>(cn, l_v, bv, total, out);
}

// Round 10
// 131.098 us; speedup vs baseline: 13.0891x; 1.6055x over previous
//
#include <hip/hip_runtime.h>
#include <math.h>

// Belief propagation (sum-product) on dense H [E x N].
// Identity: output depends only on mu_c_to_v after ITERS=8 Jacobi steps
// = (g.f)^4(0) -> 4 combined iterations.
// State: cn[c][v] = h*mu_c_to_v*w (the only way mu enters anything).
// 8-node pipeline: kA (per-row check update) alternating with kT
// (column-sum -> total, final fuses sigmoid -> out).
// NO same-address atomics (R3: 8x regression). NO cooperative grid.sync
// (R5: L2-flush -> 206 MB HBM refetch, 3x regression).
// R10: EXACT zero-row short-circuit. If P (product of nonzero T) == 0
// (underflow, same as reference cumprod) or ZC>=2, every row output is
// exactly sgn*log(1)*w = 0 -> skip w load, log chain, and cn store;
// publish flag[c]=1 ("row semantically zero; contents stale - don't read").
// kT and next kA consult flags to skip row traffic. All branches are
// block-uniform and the math is exact in every branch (general inputs
// take the full path; flag=0 rows unchanged).

constexpr int N = 4096;
constexpr int E = 2048;
constexpr int CHUNK = 16;
constexpr int BT = 256;            // threads/block (check)
constexpr int NWAVES = BT / 64;    // 4

// ---------- kA: check update, one block per row ----------
template <bool FIRST>
__global__ __launch_bounds__(BT) void kA(
    const float* __restrict__ l_v, const int* __restrict__ h,
    const int* __restrict__ s_c, const float* __restrict__ bv,
    const float* __restrict__ w, const float* __restrict__ total,
    unsigned short* __restrict__ hb, unsigned char* __restrict__ flag,
    float* __restrict__ cn)
{
    const int c = blockIdx.x;
    const int t = threadIdx.x;
    const int col0 = t * CHUNK;
    const size_t rowOff = (size_t)c * N;

    unsigned int bits;
    float m[CHUNK];
    if (FIRST) {
        const int4* h4 = reinterpret_cast<const int4*>(h + rowOff + col0);
        int4 hh[4];
        #pragma unroll
        for (int q = 0; q < 4; ++q) hh[q] = h4[q];
        const float4* lv4 = reinterpret_cast<const float4*>(l_v + col0);
        const float4* bb4 = reinterpret_cast<const float4*>(bv + col0);
        bits = 0u;
        #pragma unroll
        for (int q = 0; q < 4; ++q) {
            bits |= (hh[q].x != 0 ? 1u : 0u) << (4*q+0);
            bits |= (hh[q].y != 0 ? 1u : 0u) << (4*q+1);
            bits |= (hh[q].z != 0 ? 1u : 0u) << (4*q+2);
            bits |= (hh[q].w != 0 ? 1u : 0u) << (4*q+3);
        }
        hb[c * BT + t] = (unsigned short)bits;
        #pragma unroll
        for (int q = 0; q < 4; ++q) {
            float4 a = lv4[q], d = bb4[q];
            m[4*q+0] = a.x*d.x; m[4*q+1] = a.y*d.y;
            m[4*q+2] = a.z*d.z; m[4*q+3] = a.w*d.w;
        }
    } else {
        bits = hb[c * BT + t];
        const float4* t4 = reinterpret_cast<const float4*>(total + col0);
        float4 tv[4];
        #pragma unroll
        for (int q = 0; q < 4; ++q) tv[q] = t4[q];
        if (flag[c] == 0) {            // row has real contents (block-uniform)
            const float4* c4 = reinterpret_cast<const float4*>(cn + rowOff + col0);
            #pragma unroll
            for (int q = 0; q < 4; ++q) {
                float4 d = c4[q];
                m[4*q+0] = tv[q].x - d.x; m[4*q+1] = tv[q].y - d.y;
                m[4*q+2] = tv[q].z - d.z; m[4*q+3] = tv[q].w - d.w;
            }
        } else {                       // row semantically zero: skip 16 KB load
            #pragma unroll
            for (int q = 0; q < 4; ++q) {
                m[4*q+0] = tv[q].x; m[4*q+1] = tv[q].y;
                m[4*q+2] = tv[q].z; m[4*q+3] = tv[q].w;
            }
        }
    }

    // T = tanh(m/2) = (e^m - 1)/(e^m + 1) on fast pipes
    float T[CHUNK];
    float p = 1.f; int zc = 0;
    #pragma unroll
    for (int j = 0; j < CHUNK; ++j) {
        float mc = fminf(fmaxf(m[j], -30.f), 30.f);
        float em = __expf(mc);
        float th = (em - 1.f) * __builtin_amdgcn_rcpf(em + 1.f);
        float Tj = ((bits >> j) & 1u) ? th : 1.0f;
        T[j] = Tj;
        if (Tj == 0.f) zc++; else p *= Tj;
    }
    // wave butterfly (product of nonzeros, zero count), then cross-wave
    #pragma unroll
    for (int s = 1; s < 64; s <<= 1) {
        p  *= __shfl_xor(p, s, 64);
        zc += __shfl_xor(zc, s, 64);
    }
    __shared__ float pw[NWAVES];
    __shared__ int   zw[NWAVES];
    const int wid = t >> 6;
    if ((t & 63) == 0) { pw[wid] = p; zw[wid] = zc; }
    __syncthreads();
    float P = 1.f; int ZC = 0;
    #pragma unroll
    for (int u = 0; u < NWAVES; ++u) { P *= pw[u]; ZC += zw[u]; }

    // EXACT short-circuit: P==0 (underflow, as in reference cumprod) or
    // ZC>=2 -> all outputs are sgn*log((1+0)/(1-0))*w = 0 exactly.
    const bool zerorow = (P == 0.0f) || (ZC >= 2);
    if (!zerorow) {
        const float sgn = (s_c[c] != 0) ? -1.f : 1.f;
        const float4* w4 = reinterpret_cast<const float4*>(w + rowOff + col0);
        float4 wreg[4];
        #pragma unroll
        for (int q = 0; q < 4; ++q) wreg[q] = w4[q];
        float o[CHUNK];
        constexpr float LIM = 0.99999994f;   // 1 - 2^-24: guard div overshoot
        #pragma unroll
        for (int q = 0; q < 4; ++q) {
            float wv[4] = {wreg[q].x, wreg[q].y, wreg[q].z, wreg[q].w};
            #pragma unroll
            for (int u = 0; u < 4; ++u) {
                int j = 4*q + u;
                float excl;
                if (ZC == 0)      excl = fminf(fmaxf(__fdividef(P, T[j]), -LIM), LIM);
                else              excl = (T[j] == 0.f) ? P : 0.f;   // ZC==1 here
                // sign*2*atanh(x) = sign*ln((1+x)/(1-x)); log(1)=0 exactly
                float val = sgn * __logf(__fdividef(1.f + excl, 1.f - excl)) * wv[u];
                o[j] = ((bits >> j) & 1u) ? val : 0.f;
            }
        }
        float4* o4 = reinterpret_cast<float4*>(cn + rowOff + col0);
        #pragma unroll
        for (int q = 0; q < 4; ++q)
            o4[q] = make_float4(o[4*q+0], o[4*q+1], o[4*q+2], o[4*q+3]);
    }
    if (t == 0) flag[c] = zerorow ? (unsigned char)1 : (unsigned char)0;
}

// ---------- kT: column sum -> total (or sigmoid out), 128 blocks ----------
// 256 threads = 8 cidx x 32 slices; slice accumulates its 64 rows, skipping
// flagged (semantically-zero) rows; LDS tree over slices.
constexpr int T_BLOCKS = 128;
constexpr int T_F4C = 8;             // float4-cols per block
constexpr int T_SLICES = 32;
constexpr int T_ROWS = E / T_SLICES; // 64
constexpr unsigned long long ALL1 = 0x0101010101010101ull;

template <bool FINAL>
__global__ __launch_bounds__(BT) void kT(
    const float* __restrict__ cn, const unsigned char* __restrict__ flag,
    const float* __restrict__ l_v, const float* __restrict__ bv,
    float* __restrict__ total, float* __restrict__ out)
{
    const int t = threadIdx.x;
    const int cidx  = t & (T_F4C - 1);       // 0..7
    const int slice = t >> 3;                // 0..31
    const int f4c = blockIdx.x * T_F4C + cidx;
    const int r0 = slice * T_ROWS;

    // my slice's 64 flag bytes (8 lanes share -> broadcast, L2-hot)
    const unsigned long long* f8 = reinterpret_cast<const unsigned long long*>(flag + r0);
    unsigned long long fl[8];
    unsigned long long allskip = ~0ull;
    #pragma unroll
    for (int i = 0; i < 8; ++i) { fl[i] = f8[i]; allskip &= fl[i]; }

    float4 s = make_float4(0.f, 0.f, 0.f, 0.f);
    if (allskip != ALL1) {                   // at least one real row
        const float4* cp = reinterpret_cast<const float4*>(cn)
                           + (size_t)r0 * (N / 4) + f4c;
        #pragma unroll 8
        for (int r = 0; r < T_ROWS; ++r) {
            if (((fl[r >> 3] >> ((r & 7) * 8)) & 0xffull) == 0ull) {
                float4 v = cp[(size_t)r * (N / 4)];
                s.x += v.x; s.y += v.y; s.z += v.z; s.w += v.w;
            }
        }
    }

    __shared__ float4 red[T_SLICES][T_F4C];
    red[slice][cidx] = s;
    __syncthreads();
    #pragma unroll
    for (int hh = T_SLICES / 2; hh >= 1; hh >>= 1) {
        if (slice < hh) {
            float4 a = red[slice][cidx], b = red[slice + hh][cidx];
            red[slice][cidx] = make_float4(a.x + b.x, a.y + b.y, a.z + b.z, a.w + b.w);
        }
        __syncthreads();
    }
    if (t < T_F4C) {
        float4 sum = red[0][t];
        const int col = (blockIdx.x * T_F4C + t) * 4;
        float4 lv = *reinterpret_cast<const float4*>(l_v + col);
        float4 bb = *reinterpret_cast<const float4*>(bv + col);
        float4 r = make_float4(lv.x*bb.x + sum.x, lv.y*bb.y + sum.y,
                               lv.z*bb.z + sum.z, lv.w*bb.w + sum.w);
        if (FINAL) {
            r = make_float4(1.f/(__expf(r.x)+1.f), 1.f/(__expf(r.y)+1.f),
                            1.f/(__expf(r.z)+1.f), 1.f/(__expf(r.w)+1.f));
            *reinterpret_cast<float4*>(out + col) = r;
        } else {
            *reinterpret_cast<float4*>(total + col) = r;
        }
    }
}

extern "C" void kernel_launch(void* const* d_in, const int* in_sizes, int n_in,
                              void* d_out, int out_size, void* d_ws, size_t ws_size,
                              hipStream_t stream) {
    const float* l_v = (const float*)d_in[0];
    const int*   h   = (const int*)d_in[1];
    const int*   s_c = (const int*)d_in[2];
    // d_in[3] = iterations (8 fixed; combined = 4)
    const float* bv  = (const float*)d_in[4];
    const float* w   = (const float*)d_in[5];
    float* out = (float*)d_out;

    char* ws = (char*)d_ws;
    float* cn           = (float*)(ws);                            // 32 MB
    float* total        = (float*)(ws + (size_t)E * N * 4);        // 16 KB
    unsigned short* hb  = (unsigned short*)(ws + (size_t)E * N * 4 + (size_t)N * 4); // 1 MB
    unsigned char* flag = (unsigned char*)(ws + (size_t)E * N * 4 + (size_t)N * 4
                                           + (size_t)E * BT * 2);  // 2 KB

    kA<true ><<<E, BT, 0, stream>>>(l_v, h, s_c, bv, w, total, hb, flag, cn);
    kT<false><<<T_BLOCKS, BT, 0, stream>>>(cn, flag, l_v, bv, total, out);
    kA<false><<<E, BT, 0, stream>>>(l_v, h, s_c, bv, w, total, hb, flag, cn);
    kT<false><<<T_BLOCKS, BT, 0, stream>>>(cn, flag, l_v, bv, total, out);
    kA<false><<<E, BT, 0, stream>>>(l_v, h, s_c, bv, w, total, hb, flag, cn);
    kT<false><<<T_BLOCKS, BT, 0, stream>>>(cn, flag, l_v, bv, total, out);
    kA<false><<<E, BT, 0, stream>>>(l_v, h, s_c, bv, w, total, hb, flag, cn);
    kT<true ><<<T_BLOCKS, BT, 0, stream>>>(cn, flag, l_v, bv, total, out);
}

// Round 11
// 115.896 us; speedup vs baseline: 14.8060x; 1.1312x over previous
//
#include <hip/hip_runtime.h>
#include <math.h>

// Belief propagation (sum-product) on dense H [E x N].
// Identity: output depends only on mu_c_to_v after ITERS=8 Jacobi steps
// = (g.f)^4(0) -> 4 combined iterations.
// State: cn[c][v] = h*mu_c_to_v*w (the only way mu enters anything).
// 8-node pipeline: kA (per-row check update) alternating with kT
// (column-sum -> total, final fuses sigmoid -> out).
// NO same-address atomics (R3: 8x regression). NO cooperative grid.sync
// (R5: L2-flush -> 206 MB HBM refetch, 3x regression).
// R10: EXACT zero-row short-circuit (flag[c]=1 => row semantically zero,
// contents stale). 210 -> 131 us.
// R11: EXACT fixed-point fast exit. kT AND-reduces flags -> global
// allzero byte. If allzero: total == base and cn == 0, bitwise identical
// to the previous iteration's inputs -> the check update is the identity
// -> later kA/kT blocks return after reading ONE byte. General inputs
// (allzero==0) take the full R10 path unchanged.

constexpr int N = 4096;
constexpr int E = 2048;
constexpr int CHUNK = 16;
constexpr int BT = 256;            // threads/block (check)
constexpr int NWAVES = BT / 64;    // 4

// ---------- kA: check update, one block per row ----------
template <bool FIRST>
__global__ __launch_bounds__(BT) void kA(
    const float* __restrict__ l_v, const int* __restrict__ h,
    const int* __restrict__ s_c, const float* __restrict__ bv,
    const float* __restrict__ w, const float* __restrict__ total,
    unsigned short* __restrict__ hb, unsigned char* __restrict__ flag,
    const unsigned char* __restrict__ allzero, float* __restrict__ cn)
{
    // fixed-point fast exit: iteration is bitwise identity (see header)
    if (!FIRST && *allzero == 1) return;

    const int c = blockIdx.x;
    const int t = threadIdx.x;
    const int col0 = t * CHUNK;
    const size_t rowOff = (size_t)c * N;

    unsigned int bits;
    float m[CHUNK];
    if (FIRST) {
        const int4* h4 = reinterpret_cast<const int4*>(h + rowOff + col0);
        int4 hh[4];
        #pragma unroll
        for (int q = 0; q < 4; ++q) hh[q] = h4[q];
        const float4* lv4 = reinterpret_cast<const float4*>(l_v + col0);
        const float4* bb4 = reinterpret_cast<const float4*>(bv + col0);
        bits = 0u;
        #pragma unroll
        for (int q = 0; q < 4; ++q) {
            bits |= (hh[q].x != 0 ? 1u : 0u) << (4*q+0);
            bits |= (hh[q].y != 0 ? 1u : 0u) << (4*q+1);
            bits |= (hh[q].z != 0 ? 1u : 0u) << (4*q+2);
            bits |= (hh[q].w != 0 ? 1u : 0u) << (4*q+3);
        }
        hb[c * BT + t] = (unsigned short)bits;
        #pragma unroll
        for (int q = 0; q < 4; ++q) {
            float4 a = lv4[q], d = bb4[q];
            m[4*q+0] = a.x*d.x; m[4*q+1] = a.y*d.y;
            m[4*q+2] = a.z*d.z; m[4*q+3] = a.w*d.w;
        }
    } else {
        bits = hb[c * BT + t];
        const float4* t4 = reinterpret_cast<const float4*>(total + col0);
        float4 tv[4];
        #pragma unroll
        for (int q = 0; q < 4; ++q) tv[q] = t4[q];
        if (flag[c] == 0) {            // row has real contents (block-uniform)
            const float4* c4 = reinterpret_cast<const float4*>(cn + rowOff + col0);
            #pragma unroll
            for (int q = 0; q < 4; ++q) {
                float4 d = c4[q];
                m[4*q+0] = tv[q].x - d.x; m[4*q+1] = tv[q].y - d.y;
                m[4*q+2] = tv[q].z - d.z; m[4*q+3] = tv[q].w - d.w;
            }
        } else {                       // row semantically zero: skip 16 KB load
            #pragma unroll
            for (int q = 0; q < 4; ++q) {
                m[4*q+0] = tv[q].x; m[4*q+1] = tv[q].y;
                m[4*q+2] = tv[q].z; m[4*q+3] = tv[q].w;
            }
        }
    }

    // T = tanh(m/2) = (e^m - 1)/(e^m + 1) on fast pipes
    float T[CHUNK];
    float p = 1.f; int zc = 0;
    #pragma unroll
    for (int j = 0; j < CHUNK; ++j) {
        float mc = fminf(fmaxf(m[j], -30.f), 30.f);
        float em = __expf(mc);
        float th = (em - 1.f) * __builtin_amdgcn_rcpf(em + 1.f);
        float Tj = ((bits >> j) & 1u) ? th : 1.0f;
        T[j] = Tj;
        if (Tj == 0.f) zc++; else p *= Tj;
    }
    // wave butterfly (product of nonzeros, zero count), then cross-wave
    #pragma unroll
    for (int s = 1; s < 64; s <<= 1) {
        p  *= __shfl_xor(p, s, 64);
        zc += __shfl_xor(zc, s, 64);
    }
    __shared__ float pw[NWAVES];
    __shared__ int   zw[NWAVES];
    const int wid = t >> 6;
    if ((t & 63) == 0) { pw[wid] = p; zw[wid] = zc; }
    __syncthreads();
    float P = 1.f; int ZC = 0;
    #pragma unroll
    for (int u = 0; u < NWAVES; ++u) { P *= pw[u]; ZC += zw[u]; }

    // EXACT short-circuit: P==0 (underflow, as in reference cumprod) or
    // ZC>=2 -> all outputs are sgn*log((1+0)/(1-0))*w = 0 exactly.
    const bool zerorow = (P == 0.0f) || (ZC >= 2);
    if (!zerorow) {
        const float sgn = (s_c[c] != 0) ? -1.f : 1.f;
        const float4* w4 = reinterpret_cast<const float4*>(w + rowOff + col0);
        float4 wreg[4];
        #pragma unroll
        for (int q = 0; q < 4; ++q) wreg[q] = w4[q];
        float o[CHUNK];
        constexpr float LIM = 0.99999994f;   // 1 - 2^-24: guard div overshoot
        #pragma unroll
        for (int q = 0; q < 4; ++q) {
            float wv[4] = {wreg[q].x, wreg[q].y, wreg[q].z, wreg[q].w};
            #pragma unroll
            for (int u = 0; u < 4; ++u) {
                int j = 4*q + u;
                float excl;
                if (ZC == 0)      excl = fminf(fmaxf(__fdividef(P, T[j]), -LIM), LIM);
                else              excl = (T[j] == 0.f) ? P : 0.f;   // ZC==1 here
                // sign*2*atanh(x) = sign*ln((1+x)/(1-x)); log(1)=0 exactly
                float val = sgn * __logf(__fdividef(1.f + excl, 1.f - excl)) * wv[u];
                o[j] = ((bits >> j) & 1u) ? val : 0.f;
            }
        }
        float4* o4 = reinterpret_cast<float4*>(cn + rowOff + col0);
        #pragma unroll
        for (int q = 0; q < 4; ++q)
            o4[q] = make_float4(o[4*q+0], o[4*q+1], o[4*q+2], o[4*q+3]);
    }
    if (t == 0) flag[c] = zerorow ? (unsigned char)1 : (unsigned char)0;
}

// ---------- kT: column sum -> total (or sigmoid out), 128 blocks ----------
// 256 threads = 8 cidx x 32 slices; slice accumulates its 64 rows, skipping
// flagged rows; LDS tree over slices. Also AND-reduces flags -> allzero.
constexpr int T_BLOCKS = 128;
constexpr int T_F4C = 8;             // float4-cols per block
constexpr int T_SLICES = 32;
constexpr int T_ROWS = E / T_SLICES; // 64
constexpr unsigned long long ALL1 = 0x0101010101010101ull;

template <bool SKIP, bool FINAL>
__global__ __launch_bounds__(BT) void kT(
    const float* __restrict__ cn, const unsigned char* __restrict__ flag,
    const float* __restrict__ l_v, const float* __restrict__ bv,
    float* __restrict__ total, unsigned char* __restrict__ allzero,
    float* __restrict__ out)
{
    // fixed-point fast exit: total already == base, flags unchanged
    if (SKIP && !FINAL && *allzero == 1) return;

    const int t = threadIdx.x;
    const int cidx  = t & (T_F4C - 1);       // 0..7
    const int slice = t >> 3;                // 0..31
    const int f4c = blockIdx.x * T_F4C + cidx;
    const int r0 = slice * T_ROWS;

    // my slice's 64 flag bytes (8 lanes share -> broadcast, L2-hot)
    const unsigned long long* f8 = reinterpret_cast<const unsigned long long*>(flag + r0);
    unsigned long long fl[8];
    unsigned long long allskip = ~0ull;
    #pragma unroll
    for (int i = 0; i < 8; ++i) { fl[i] = f8[i]; allskip &= fl[i]; }

    float4 s = make_float4(0.f, 0.f, 0.f, 0.f);
    if (allskip != ALL1) {                   // at least one real row
        const float4* cp = reinterpret_cast<const float4*>(cn)
                           + (size_t)r0 * (N / 4) + f4c;
        #pragma unroll 8
        for (int r = 0; r < T_ROWS; ++r) {
            if (((fl[r >> 3] >> ((r & 7) * 8)) & 0xffull) == 0ull) {
                float4 v = cp[(size_t)r * (N / 4)];
                s.x += v.x; s.y += v.y; s.z += v.z; s.w += v.w;
            }
        }
    }

    __shared__ float4 red[T_SLICES][T_F4C];
    __shared__ unsigned char andv[T_SLICES];
    red[slice][cidx] = s;
    if (cidx == 0) andv[slice] = (allskip == ALL1) ? 1 : 0;
    __syncthreads();
    #pragma unroll
    for (int hh = T_SLICES / 2; hh >= 1; hh >>= 1) {
        if (slice < hh) {
            float4 a = red[slice][cidx], b = red[slice + hh][cidx];
            red[slice][cidx] = make_float4(a.x + b.x, a.y + b.y, a.z + b.z, a.w + b.w);
        }
        __syncthreads();
    }
    if (t < T_F4C) {
        float4 sum = red[0][t];
        const int col = (blockIdx.x * T_F4C + t) * 4;
        float4 lv = *reinterpret_cast<const float4*>(l_v + col);
        float4 bb = *reinterpret_cast<const float4*>(bv + col);
        float4 r = make_float4(lv.x*bb.x + sum.x, lv.y*bb.y + sum.y,
                               lv.z*bb.z + sum.z, lv.w*bb.w + sum.w);
        if (FINAL) {
            r = make_float4(1.f/(__expf(r.x)+1.f), 1.f/(__expf(r.y)+1.f),
                            1.f/(__expf(r.z)+1.f), 1.f/(__expf(r.w)+1.f));
            *reinterpret_cast<float4*>(out + col) = r;
        } else {
            *reinterpret_cast<float4*>(total + col) = r;
        }
    }
    if (!FINAL && blockIdx.x == 0 && t == 0) {
        unsigned char az = 1;
        #pragma unroll
        for (int u = 0; u < T_SLICES; ++u) az &= andv[u];
        *allzero = az;
    }
}

extern "C" void kernel_launch(void* const* d_in, const int* in_sizes, int n_in,
                              void* d_out, int out_size, void* d_ws, size_t ws_size,
                              hipStream_t stream) {
    const float* l_v = (const float*)d_in[0];
    const int*   h   = (const int*)d_in[1];
    const int*   s_c = (const int*)d_in[2];
    // d_in[3] = iterations (8 fixed; combined = 4)
    const float* bv  = (const float*)d_in[4];
    const float* w   = (const float*)d_in[5];
    float* out = (float*)d_out;

    char* ws = (char*)d_ws;
    float* cn           = (float*)(ws);                            // 32 MB
    float* total        = (float*)(ws + (size_t)E * N * 4);        // 16 KB
    unsigned short* hb  = (unsigned short*)(ws + (size_t)E * N * 4 + (size_t)N * 4); // 1 MB
    unsigned char* flag = (unsigned char*)(ws + (size_t)E * N * 4 + (size_t)N * 4
                                           + (size_t)E * BT * 2);  // 2 KB
    unsigned char* allzero = flag + E;                             // 1 B

    kA<true ><<<E, BT, 0, stream>>>(l_v, h, s_c, bv, w, total, hb, flag, allzero, cn);
    kT<false,false><<<T_BLOCKS, BT, 0, stream>>>(cn, flag, l_v, bv, total, allzero, out);
    kA<false><<<E, BT, 0, stream>>>(l_v, h, s_c, bv, w, total, hb, flag, allzero, cn);
    kT<true, false><<<T_BLOCKS, BT, 0, stream>>>(cn, flag, l_v, bv, total, allzero, out);
    kA<false><<<E, BT, 0, stream>>>(l_v, h, s_c, bv, w, total, hb, flag, allzero, cn);
    kT<true, false><<<T_BLOCKS, BT, 0, stream>>>(cn, flag, l_v, bv, total, allzero, out);
    kA<false><<<E, BT, 0, stream>>>(l_v, h, s_c, bv, w, total, hb, flag, allzero, cn);
    kT<true, true ><<<T_BLOCKS, BT, 0, stream>>>(cn, flag, l_v, bv, total, allzero, out);
}